// Round 3
// baseline (963.490 us; speedup 1.0000x reference)
//
#include <hip/hip_runtime.h>
#include <hip/hip_bf16.h>
#include <math.h>

#define N_NODES 50000
#define N_EDGES 800000
#define E_TOT   850000   // N_EDGES + N_NODES self-loops
#define SCAN_B  1024

typedef __hip_bfloat16 bf16;

static __device__ __forceinline__ float b2f(bf16 v) { return __bfloat162float(v); }

// load a float from an input buffer whose device dtype is bf16 (BF=true) or fp32
template<bool BF>
static __device__ __forceinline__ float ldv(const void* p, int i) {
    if constexpr (BF)
        return __uint_as_float(((unsigned int)((const unsigned short*)p)[i]) << 16);
    else
        return ((const float*)p)[i];
}

// ------------------------- dtype detection (device) ------------------------
// flags[0]=1 if float inputs are bf16; flags[1]=1 if edge_index is int64.
__global__ void k_detect(const unsigned int* __restrict__ x32,
                         const unsigned int* __restrict__ ei32,
                         int* __restrict__ flags) {
    if (threadIdx.x == 0 && blockIdx.x == 0) {
        // bf16 data: bits[14:7] of each 32b word = a bf16 exponent, ~[117,129] for N(0,1)
        // fp32 data: bits[14:7] = middle mantissa bits, uniform random
        int cnt = 0;
        for (int i = 0; i < 256; i++) {
            unsigned int e = (x32[i] >> 7) & 0xFF;
            cnt += (e >= 90 && e <= 140) ? 1 : 0;
        }
        flags[0] = (cnt >= 128) ? 1 : 0;
        // int64 edges: high (odd) words are all zero (values < 50000)
        int z = 0;
        for (int i = 0; i < 64; i++) z += (ei32[2 * i + 1] == 0) ? 1 : 0;
        flags[1] = (z >= 48) ? 1 : 0;
    }
}

// ------------------------------ CSR build ---------------------------------
__global__ void k_zero(int* __restrict__ p, int n) {
    int i = blockIdx.x * blockDim.x + threadIdx.x;
    if (i < n) p[i] = 0;
}

template<bool I64>
__global__ void k_hist(const int* __restrict__ flags, const void* __restrict__ ei,
                       int* __restrict__ counts) {
    if ((flags[1] != 0) != I64) return;
    int i = blockIdx.x * blockDim.x + threadIdx.x;
    if (i >= E_TOT) return;
    int d;
    if (i < N_EDGES)
        d = I64 ? (int)((const long long*)ei)[N_EDGES + i] : ((const int*)ei)[N_EDGES + i];
    else
        d = i - N_EDGES;
    atomicAdd(&counts[d], 1);
}

__global__ void k_scan1(const int* __restrict__ counts, int* __restrict__ scanned,
                        int* __restrict__ partial, int n) {
    __shared__ int sh[SCAN_B];
    int i = blockIdx.x * SCAN_B + threadIdx.x;
    sh[threadIdx.x] = (i < n) ? counts[i] : 0;
    __syncthreads();
    for (int off = 1; off < SCAN_B; off <<= 1) {
        int t = (threadIdx.x >= off) ? sh[threadIdx.x - off] : 0;
        __syncthreads();
        sh[threadIdx.x] += t;
        __syncthreads();
    }
    if (i < n) scanned[i] = sh[threadIdx.x];
    if (threadIdx.x == SCAN_B - 1) partial[blockIdx.x] = sh[SCAN_B - 1];
}

__global__ void k_scan2(int* __restrict__ partial, int nb) {
    if (threadIdx.x == 0 && blockIdx.x == 0) {
        int acc = 0;
        for (int b = 0; b < nb; b++) { int t = partial[b]; partial[b] = acc; acc += t; }
    }
}

__global__ void k_scan3(const int* __restrict__ counts, const int* __restrict__ scanned,
                        const int* __restrict__ partial, int* __restrict__ rowptr,
                        int* __restrict__ cursor, int n) {
    int i = blockIdx.x * blockDim.x + threadIdx.x;
    if (i >= n) return;
    int incl = scanned[i] + partial[i / SCAN_B];
    rowptr[i + 1] = incl;
    cursor[i]     = incl - counts[i];
    if (i == 0) rowptr[0] = 0;
}

template<bool I64>
__global__ void k_scatter(const int* __restrict__ flags, const void* __restrict__ ei,
                          int* __restrict__ cursor, int* __restrict__ csr_src) {
    if ((flags[1] != 0) != I64) return;
    int i = blockIdx.x * blockDim.x + threadIdx.x;
    if (i >= E_TOT) return;
    int s, d;
    if (i < N_EDGES) {
        if constexpr (I64) {
            s = (int)((const long long*)ei)[i];
            d = (int)((const long long*)ei)[N_EDGES + i];
        } else {
            s = ((const int*)ei)[i];
            d = ((const int*)ei)[N_EDGES + i];
        }
    } else {
        s = d = i - N_EDGES;
    }
    int pos = atomicAdd(&cursor[d], 1);
    csr_src[pos] = s;
}

// ------------------------------ GEMM: xp = h @ W ---------------------------
// W staged as bf16 in LDS (converted if fp32); fp32 accumulate; xp stored bf16.
// XBF: input activation dtype is bf16. WBF: weight (global input) dtype is bf16.
template<int K, int NT, int NTB, bool XBF, bool WBF>
__global__ __launch_bounds__(256) void k_gemm(const int* __restrict__ flags,
                                              const void* __restrict__ hv,
                                              const void* __restrict__ W,
                                              bf16* __restrict__ xp) {
    if ((flags[0] != 0) != WBF) return;
    constexpr int COLB = NT / NTB;     // column blocks
    constexpr int TPR  = NTB / 2;      // threads per row
    constexpr int RG   = 256 / TPR;    // rows per group
    __shared__ unsigned short Ws[K * NTB];   // <= 32KB
    __shared__ float hs[RG][K];              // <= 8KB

    const int cb = blockIdx.x % COLB;
    for (int idx = threadIdx.x; idx < K * NTB; idx += 256) {
        int k = idx / NTB, c = idx - k * NTB;
        unsigned short w;
        if constexpr (WBF) {
            w = ((const unsigned short*)W)[k * NT + cb * NTB + c];
        } else {
            unsigned int u = __float_as_uint(((const float*)W)[k * NT + cb * NTB + c]);
            w = (unsigned short)((u + 0x7FFFu + ((u >> 16) & 1u)) >> 16);  // RNE to bf16
        }
        Ws[idx] = w;
    }
    const int r  = threadIdx.x / TPR;
    const int cl = (threadIdx.x % TPR) * 2;
    const int ngroups = (N_NODES + RG - 1) / RG;
    const int g0 = blockIdx.x / COLB;
    const int gs = gridDim.x / COLB;
    for (int g = g0; g < ngroups; g += gs) {
        const int row0 = g * RG;
        __syncthreads();                       // protects hs reuse + initial Ws stage
        for (int idx = threadIdx.x; idx < RG * K; idx += 256) {
            int rr = idx / K, kk = idx - rr * K;
            int row = row0 + rr;
            hs[rr][kk] = (row < N_NODES) ? ldv<XBF>(hv, row * K + kk) : 0.f;
        }
        __syncthreads();
        const int row = row0 + r;
        if (row < N_NODES) {
            float acc0 = 0.f, acc1 = 0.f;
            #pragma unroll 16
            for (int k = 0; k < K; k++) {
                float hvk = hs[r][k];
                unsigned int w01 = *(const unsigned int*)&Ws[k * NTB + cl];
                acc0 = fmaf(hvk, __uint_as_float(w01 << 16),         acc0);
                acc1 = fmaf(hvk, __uint_as_float(w01 & 0xffff0000u), acc1);
            }
            __hip_bfloat162 v2;
            v2.x = __float2bfloat16(acc0);
            v2.y = __float2bfloat16(acc1);
            *(__hip_bfloat162*)&xp[(size_t)row * NT + cb * NTB + cl] = v2;
        }
    }
}

// ---------------------- per-node attention dot products --------------------
// PBF: parameter (att vectors) dtype is bf16. xp is always bf16 (internal).
template<int CT, int H, bool PBF>
__global__ __launch_bounds__(CT) void k_attdots(const int* __restrict__ flags,
                                                const bf16* __restrict__ xp,
                                                const void* __restrict__ att_s,
                                                const void* __restrict__ att_d,
                                                float* __restrict__ asr,
                                                float* __restrict__ adst) {
    if ((flags[0] != 0) != PBF) return;
    constexpr int C = CT / H;
    __shared__ float s1[CT], s2[CT];
    const int t = threadIdx.x;
    const float wsv = ldv<PBF>(att_s, t);
    const float wdv = ldv<PBF>(att_d, t);
    for (int n = blockIdx.x; n < N_NODES; n += gridDim.x) {
        float v = b2f(xp[(size_t)n * CT + t]);
        __syncthreads();
        s1[t] = v * wsv;
        s2[t] = v * wdv;
        __syncthreads();
        #pragma unroll
        for (int off = C / 2; off > 0; off >>= 1) {
            if ((t & (C - 1)) < off) { s1[t] += s1[t + off]; s2[t] += s2[t + off]; }
            __syncthreads();
        }
        if ((t & (C - 1)) == 0) {
            int hh = t / C;
            asr[n * H + hh]  = s1[t];
            adst[n * H + hh] = s2[t];
        }
    }
}

// -------- fused edge-softmax + aggregation + bias (+ LayerNorm + ELU) ------
// One block per node. Thread t: head hd = t/C, channel/edge-slot e_loc = t%C.
template<int CT, int H, bool LAST, bool PBF>
__global__ __launch_bounds__(CT) void k_agg(const int* __restrict__ flags,
                                            const bf16* __restrict__ xp,
                                            const float* __restrict__ asr,
                                            const float* __restrict__ adst,
                                            const int* __restrict__ rowptr,
                                            const int* __restrict__ csr_src,
                                            const void* __restrict__ bias,
                                            const void* __restrict__ gamma,
                                            const void* __restrict__ beta,
                                            void* __restrict__ outv) {
    if ((flags[0] != 0) != PBF) return;
    constexpr int C = CT / H;     // channels per head == edge chunk size
    const int t     = threadIdx.x;
    const int hd    = t / C;
    const int e_loc = t % C;

    __shared__ int   sn_sh[C];
    __shared__ float al_sh[C * H];
    __shared__ float red[CT], red2[CT];
    __shared__ float mw[2], sw[2];

    for (int n = blockIdx.x; n < N_NODES; n += gridDim.x) {
        const int b0 = rowptr[n], b1 = rowptr[n + 1];
        const int deg = b1 - b0;
        const float ad = adst[n * H + hd];

        // pass 1: online (max, sum) over softmax logits, edges strided over lanes
        float m = -1e30f, s = 0.f;
        for (int j = b0 + e_loc; j < b1; j += C) {
            int sn = csr_src[j];
            float e = asr[sn * H + hd] + ad;
            e = e > 0.f ? e : 0.2f * e;
            float mn = fmaxf(m, e);
            s = s * __expf(m - mn) + __expf(e - mn);
            m = mn;
        }
        #pragma unroll
        for (int off = 1; off < 64; off <<= 1) {   // wave reduce (head groups wave-aligned)
            float mo = __shfl_xor(m, off);
            float so = __shfl_xor(s, off);
            float mn = fmaxf(m, mo);
            s = s * __expf(m - mn) + so * __expf(mo - mn);
            m = mn;
        }
        if constexpr (C == 128) {                  // one head spanning 2 waves
            __syncthreads();
            if ((t & 63) == 0) { mw[t >> 6] = m; sw[t >> 6] = s; }
            __syncthreads();
            float m0 = mw[0], m1 = mw[1], s0 = sw[0], s1v = sw[1];
            float mn = fmaxf(m0, m1);
            m = mn;
            s = s0 * __expf(m0 - mn) + s1v * __expf(m1 - mn);
        }
        const float inv_s = 1.f / s;
        const float mreg  = m;

        // pass 2: chunked alpha staging + gather-accumulate
        float acc = 0.f;
        for (int cbase = 0; cbase < deg; cbase += C) {
            const int nn = min(C, deg - cbase);
            __syncthreads();                       // protect sn_sh/al_sh reuse
            if (e_loc < nn) {
                int j  = b0 + cbase + e_loc;
                int sn = csr_src[j];
                if (hd == 0) sn_sh[e_loc] = sn;
                float e = asr[sn * H + hd] + ad;
                e = e > 0.f ? e : 0.2f * e;
                al_sh[e_loc * H + hd] = __expf(e - mreg) * inv_s;
            }
            __syncthreads();
            for (int e = 0; e < nn; e++) {
                acc = fmaf(al_sh[e * H + hd], b2f(xp[(size_t)sn_sh[e] * CT + t]), acc);
            }
        }
        acc += ldv<PBF>(bias, t);

        if constexpr (!LAST) {
            // LayerNorm over CT + ELU, write bf16 h for next layer
            red[t] = acc; red2[t] = acc * acc;
            __syncthreads();
            #pragma unroll
            for (int off = CT / 2; off > 0; off >>= 1) {
                if (t < off) { red[t] += red[t + off]; red2[t] += red2[t + off]; }
                __syncthreads();
            }
            float mu  = red[0] * (1.f / CT);
            float var = red2[0] * (1.f / CT) - mu * mu;
            float y = (acc - mu) * rsqrtf(var + 1e-5f) * ldv<PBF>(gamma, t) + ldv<PBF>(beta, t);
            y = y > 0.f ? y : expm1f(y);
            ((bf16*)outv)[(size_t)n * CT + t] = __float2bfloat16(y);
        } else {
            if constexpr (PBF)
                ((bf16*)outv)[(size_t)n * CT + t] = __float2bfloat16(acc);
            else
                ((float*)outv)[(size_t)n * CT + t] = acc;
        }
    }
}

// --------------------------------- launcher --------------------------------
extern "C" void kernel_launch(void* const* d_in, const int* in_sizes, int n_in,
                              void* d_out, int out_size, void* d_ws, size_t ws_size,
                              hipStream_t stream) {
    const void* x   = d_in[0];
    const void* ei  = d_in[1];
    const void* W1  = d_in[2];
    const void* as1 = d_in[3];
    const void* ad1 = d_in[4];
    const void* b1  = d_in[5];
    const void* g1  = d_in[6];
    const void* be1 = d_in[7];
    const void* W2  = d_in[8];
    const void* as2 = d_in[9];
    const void* ad2 = d_in[10];
    const void* b2  = d_in[11];
    const void* g2  = d_in[12];
    const void* be2 = d_in[13];
    const void* W3  = d_in[14];
    const void* as3 = d_in[15];
    const void* ad3 = d_in[16];
    const void* b3  = d_in[17];

    char* ws = (char*)d_ws;
    bf16*  xp     = (bf16*)(ws);                // [N,256] bf16 = 25,600,000 B
    bf16*  hbuf   = (bf16*)(ws + 25600000);     // [N,256] bf16 = 25,600,000 B
    float* asr    = (float*)(ws + 51200000);    //    800,000 B
    float* adst   = (float*)(ws + 52000000);    //    800,000 B
    int*   counts = (int*)  (ws + 52800000);    //    200,000 B
    int*   scannd = (int*)  (ws + 53000000);    //    200,000 B
    int*   part   = (int*)  (ws + 53200000);    //        256 B
    int*   rowptr = (int*)  (ws + 53200256);    //    200,004 B
    int*   cursor = (int*)  (ws + 53400260);    //    200,000 B
    int*   csrsrc = (int*)  (ws + 53600260);    //  3,400,000 B
    int*   flags  = (int*)  (ws + 57000260);    //         16 B  (end ~57.0 MB)

    const int nb_scan = (N_NODES + SCAN_B - 1) / SCAN_B;

    k_detect<<<1, 64, 0, stream>>>((const unsigned int*)x, (const unsigned int*)ei, flags);

    k_zero<<<(N_NODES + 255) / 256, 256, 0, stream>>>(counts, N_NODES);
    k_hist<false><<<(E_TOT + 255) / 256, 256, 0, stream>>>(flags, ei, counts);
    k_hist<true ><<<(E_TOT + 255) / 256, 256, 0, stream>>>(flags, ei, counts);
    k_scan1<<<nb_scan, SCAN_B, 0, stream>>>(counts, scannd, part, N_NODES);
    k_scan2<<<1, 64, 0, stream>>>(part, nb_scan);
    k_scan3<<<(N_NODES + 255) / 256, 256, 0, stream>>>(counts, scannd, part, rowptr, cursor, N_NODES);
    k_scatter<false><<<(E_TOT + 255) / 256, 256, 0, stream>>>(flags, ei, cursor, csrsrc);
    k_scatter<true ><<<(E_TOT + 255) / 256, 256, 0, stream>>>(flags, ei, cursor, csrsrc);

    // ---- layer 1: in 128 -> xp [N,256], H=4, C=64
    k_gemm<128, 256, 128, false, false><<<2048, 256, 0, stream>>>(flags, x, W1, xp);
    k_gemm<128, 256, 128, true,  true ><<<2048, 256, 0, stream>>>(flags, x, W1, xp);
    k_attdots<256, 4, false><<<N_NODES, 256, 0, stream>>>(flags, xp, as1, ad1, asr, adst);
    k_attdots<256, 4, true ><<<N_NODES, 256, 0, stream>>>(flags, xp, as1, ad1, asr, adst);
    k_agg<256, 4, false, false><<<N_NODES, 256, 0, stream>>>(flags, xp, asr, adst, rowptr, csrsrc, b1, g1, be1, hbuf);
    k_agg<256, 4, false, true ><<<N_NODES, 256, 0, stream>>>(flags, xp, asr, adst, rowptr, csrsrc, b1, g1, be1, hbuf);

    // ---- layer 2: in 256 (bf16 hbuf) -> xp [N,128], H=2, C=64
    k_gemm<256, 128, 64, true, false><<<2048, 256, 0, stream>>>(flags, hbuf, W2, xp);
    k_gemm<256, 128, 64, true, true ><<<2048, 256, 0, stream>>>(flags, hbuf, W2, xp);
    k_attdots<128, 2, false><<<N_NODES, 128, 0, stream>>>(flags, xp, as2, ad2, asr, adst);
    k_attdots<128, 2, true ><<<N_NODES, 128, 0, stream>>>(flags, xp, as2, ad2, asr, adst);
    k_agg<128, 2, false, false><<<N_NODES, 128, 0, stream>>>(flags, xp, asr, adst, rowptr, csrsrc, b2, g2, be2, hbuf);
    k_agg<128, 2, false, true ><<<N_NODES, 128, 0, stream>>>(flags, xp, asr, adst, rowptr, csrsrc, b2, g2, be2, hbuf);

    // ---- layer 3: in 128 (bf16 hbuf) -> xp [N,128], H=1, C=128; write d_out
    k_gemm<128, 128, 128, true, false><<<2048, 256, 0, stream>>>(flags, hbuf, W3, xp);
    k_gemm<128, 128, 128, true, true ><<<2048, 256, 0, stream>>>(flags, hbuf, W3, xp);
    k_attdots<128, 1, false><<<N_NODES, 128, 0, stream>>>(flags, xp, as3, ad3, asr, adst);
    k_attdots<128, 1, true ><<<N_NODES, 128, 0, stream>>>(flags, xp, as3, ad3, asr, adst);
    k_agg<128, 1, true, false><<<N_NODES, 128, 0, stream>>>(flags, xp, asr, adst, rowptr, csrsrc, b3, nullptr, nullptr, d_out);
    k_agg<128, 1, true, true ><<<N_NODES, 128, 0, stream>>>(flags, xp, asr, adst, rowptr, csrsrc, b3, nullptr, nullptr, d_out);
}

// Round 4
// 592.510 us; speedup vs baseline: 1.6261x; 1.6261x over previous
//
#include <hip/hip_runtime.h>
#include <hip/hip_bf16.h>
#include <math.h>

#define N_NODES 50000
#define N_EDGES 800000
#define E_TOT   850000   // N_EDGES + N_NODES self-loops
#define SCAN_B  1024

typedef __hip_bfloat16 bf16;

static __device__ __forceinline__ float b2f(bf16 v) { return __bfloat162float(v); }
static __device__ __forceinline__ float u2f(unsigned short u) {
    return __uint_as_float(((unsigned int)u) << 16);
}
static __device__ __forceinline__ unsigned short f2u(float f) {   // RNE f32->bf16
    unsigned int u = __float_as_uint(f);
    return (unsigned short)((u + 0x7FFFu + ((u >> 16) & 1u)) >> 16);
}

// load a float from an input buffer whose device dtype is bf16 (BF=true) or fp32
template<bool BF>
static __device__ __forceinline__ float ldv(const void* p, int i) {
    if constexpr (BF)
        return u2f(((const unsigned short*)p)[i]);
    else
        return ((const float*)p)[i];
}

// load V consecutive bf16 (vectorized) and convert to float
template<int V>
static __device__ __forceinline__ void ldbf(const bf16* p, float* out) {
    if constexpr (V == 4) {
        ushort4 u = *(const ushort4*)p;
        out[0] = u2f(u.x); out[1] = u2f(u.y); out[2] = u2f(u.z); out[3] = u2f(u.w);
    } else {
        ushort2 u = *(const ushort2*)p;
        out[0] = u2f(u.x); out[1] = u2f(u.y);
    }
}

// ------------------------- dtype detection (device) ------------------------
__global__ void k_detect(const unsigned int* __restrict__ x32,
                         const unsigned int* __restrict__ ei32,
                         int* __restrict__ flags) {
    if (threadIdx.x == 0 && blockIdx.x == 0) {
        int cnt = 0;
        for (int i = 0; i < 256; i++) {
            unsigned int e = (x32[i] >> 7) & 0xFF;
            cnt += (e >= 90 && e <= 140) ? 1 : 0;
        }
        flags[0] = (cnt >= 128) ? 1 : 0;
        int z = 0;
        for (int i = 0; i < 64; i++) z += (ei32[2 * i + 1] == 0) ? 1 : 0;
        flags[1] = (z >= 48) ? 1 : 0;
    }
}

// ------------------------------ CSR build ---------------------------------
__global__ void k_zero(int* __restrict__ p, int n) {
    int i = blockIdx.x * blockDim.x + threadIdx.x;
    if (i < n) p[i] = 0;
}

template<bool I64>
__global__ void k_hist(const int* __restrict__ flags, const void* __restrict__ ei,
                       int* __restrict__ counts) {
    if ((flags[1] != 0) != I64) return;
    int i = blockIdx.x * blockDim.x + threadIdx.x;
    if (i >= E_TOT) return;
    int d;
    if (i < N_EDGES)
        d = I64 ? (int)((const long long*)ei)[N_EDGES + i] : ((const int*)ei)[N_EDGES + i];
    else
        d = i - N_EDGES;
    atomicAdd(&counts[d], 1);
}

__global__ void k_scan1(const int* __restrict__ counts, int* __restrict__ scanned,
                        int* __restrict__ partial, int n) {
    __shared__ int sh[SCAN_B];
    int i = blockIdx.x * SCAN_B + threadIdx.x;
    sh[threadIdx.x] = (i < n) ? counts[i] : 0;
    __syncthreads();
    for (int off = 1; off < SCAN_B; off <<= 1) {
        int t = (threadIdx.x >= off) ? sh[threadIdx.x - off] : 0;
        __syncthreads();
        sh[threadIdx.x] += t;
        __syncthreads();
    }
    if (i < n) scanned[i] = sh[threadIdx.x];
    if (threadIdx.x == SCAN_B - 1) partial[blockIdx.x] = sh[SCAN_B - 1];
}

__global__ void k_scan2(int* __restrict__ partial, int nb) {
    if (threadIdx.x == 0 && blockIdx.x == 0) {
        int acc = 0;
        for (int b = 0; b < nb; b++) { int t = partial[b]; partial[b] = acc; acc += t; }
    }
}

__global__ void k_scan3(const int* __restrict__ counts, const int* __restrict__ scanned,
                        const int* __restrict__ partial, int* __restrict__ rowptr,
                        int* __restrict__ cursor, int n) {
    int i = blockIdx.x * blockDim.x + threadIdx.x;
    if (i >= n) return;
    int incl = scanned[i] + partial[i / SCAN_B];
    rowptr[i + 1] = incl;
    cursor[i]     = incl - counts[i];
    if (i == 0) rowptr[0] = 0;
}

template<bool I64>
__global__ void k_scatter(const int* __restrict__ flags, const void* __restrict__ ei,
                          int* __restrict__ cursor, int* __restrict__ csr_src) {
    if ((flags[1] != 0) != I64) return;
    int i = blockIdx.x * blockDim.x + threadIdx.x;
    if (i >= E_TOT) return;
    int s, d;
    if (i < N_EDGES) {
        if constexpr (I64) {
            s = (int)((const long long*)ei)[i];
            d = (int)((const long long*)ei)[N_EDGES + i];
        } else {
            s = ((const int*)ei)[i];
            d = ((const int*)ei)[N_EDGES + i];
        }
    } else {
        s = d = i - N_EDGES;
    }
    int pos = atomicAdd(&cursor[d], 1);
    csr_src[pos] = s;
}

// ------------------------------ GEMM: xp = h @ W ---------------------------
template<int K, int NT, int NTB, bool XBF, bool WBF>
__global__ __launch_bounds__(256) void k_gemm(const int* __restrict__ flags,
                                              const void* __restrict__ hv,
                                              const void* __restrict__ W,
                                              bf16* __restrict__ xp) {
    if ((flags[0] != 0) != WBF) return;
    constexpr int COLB = NT / NTB;
    constexpr int TPR  = NTB / 2;
    constexpr int RG   = 256 / TPR;
    __shared__ unsigned short Ws[K * NTB];
    __shared__ float hs[RG][K];

    const int cb = blockIdx.x % COLB;
    for (int idx = threadIdx.x; idx < K * NTB; idx += 256) {
        int k = idx / NTB, c = idx - k * NTB;
        unsigned short w;
        if constexpr (WBF) {
            w = ((const unsigned short*)W)[k * NT + cb * NTB + c];
        } else {
            w = f2u(((const float*)W)[k * NT + cb * NTB + c]);
        }
        Ws[idx] = w;
    }
    const int r  = threadIdx.x / TPR;
    const int cl = (threadIdx.x % TPR) * 2;
    const int ngroups = (N_NODES + RG - 1) / RG;
    const int g0 = blockIdx.x / COLB;
    const int gs = gridDim.x / COLB;
    for (int g = g0; g < ngroups; g += gs) {
        const int row0 = g * RG;
        __syncthreads();
        for (int idx = threadIdx.x; idx < RG * K; idx += 256) {
            int rr = idx / K, kk = idx - rr * K;
            int row = row0 + rr;
            hs[rr][kk] = (row < N_NODES) ? ldv<XBF>(hv, row * K + kk) : 0.f;
        }
        __syncthreads();
        const int row = row0 + r;
        if (row < N_NODES) {
            float acc0 = 0.f, acc1 = 0.f;
            #pragma unroll 16
            for (int k = 0; k < K; k++) {
                float hvk = hs[r][k];
                unsigned int w01 = *(const unsigned int*)&Ws[k * NTB + cl];
                acc0 = fmaf(hvk, __uint_as_float(w01 << 16),         acc0);
                acc1 = fmaf(hvk, __uint_as_float(w01 & 0xffff0000u), acc1);
            }
            __hip_bfloat162 v2;
            v2.x = __float2bfloat16(acc0);
            v2.y = __float2bfloat16(acc1);
            *(__hip_bfloat162*)&xp[(size_t)row * NT + cb * NTB + cl] = v2;
        }
    }
}

// ---------------------- per-node attention dot products --------------------
// One wave per node, V = CT/64 channels per lane, shfl reduce, no LDS/barriers.
template<int CT, int H, int V, bool PBF>
__global__ __launch_bounds__(256) void k_attdots2(const int* __restrict__ flags,
                                                  const bf16* __restrict__ xp,
                                                  const void* __restrict__ att_s,
                                                  const void* __restrict__ att_d,
                                                  float* __restrict__ asr,
                                                  float* __restrict__ adst) {
    if ((flags[0] != 0) != PBF) return;
    constexpr int LPH = (CT / H) / V;       // lanes per head group
    const int l    = threadIdx.x & 63;
    const int w    = threadIdx.x >> 6;
    const int hd   = l / LPH;
    const int slot = l & (LPH - 1);
    float ws[V], wd[V];
    #pragma unroll
    for (int v = 0; v < V; v++) {
        ws[v] = ldv<PBF>(att_s, V * l + v);
        wd[v] = ldv<PBF>(att_d, V * l + v);
    }
    for (int n = blockIdx.x * 4 + w; n < N_NODES; n += gridDim.x * 4) {
        float xv[V];
        ldbf<V>(xp + (size_t)n * CT + V * l, xv);
        float s1 = 0.f, s2 = 0.f;
        #pragma unroll
        for (int v = 0; v < V; v++) { s1 = fmaf(xv[v], ws[v], s1); s2 = fmaf(xv[v], wd[v], s2); }
        #pragma unroll
        for (int off = 1; off < LPH; off <<= 1) {
            s1 += __shfl_xor(s1, off);
            s2 += __shfl_xor(s2, off);
        }
        if (slot == 0) {
            asr[n * H + hd]  = s1;
            adst[n * H + hd] = s2;
        }
    }
}

// -------- fused edge-softmax + aggregation + bias (+ LayerNorm + ELU) ------
// One wave per node, V channels per lane, alpha shared via shfl. No LDS, no
// __syncthreads -> 4 fully independent node-waves per block.
template<int CT, int H, int V, bool LAST, bool PBF>
__global__ __launch_bounds__(256) void k_agg2(const int* __restrict__ flags,
                                              const bf16* __restrict__ xp,
                                              const float* __restrict__ asr,
                                              const float* __restrict__ adst,
                                              const int* __restrict__ rowptr,
                                              const int* __restrict__ csr_src,
                                              const void* __restrict__ bias,
                                              const void* __restrict__ gamma,
                                              const void* __restrict__ beta,
                                              void* __restrict__ outv) {
    if ((flags[0] != 0) != PBF) return;
    constexpr int C   = CT / H;
    constexpr int LPH = C / V;              // lanes per head group == edge chunk
    const int l     = threadIdx.x & 63;
    const int w     = threadIdx.x >> 6;
    const int hd    = l / LPH;
    const int slot  = l & (LPH - 1);
    const int lbase = l - slot;

    float bv[V];
    #pragma unroll
    for (int v = 0; v < V; v++) bv[v] = ldv<PBF>(bias, V * l + v);
    float gv[V], bev[V];
    if constexpr (!LAST) {
        #pragma unroll
        for (int v = 0; v < V; v++) {
            gv[v]  = ldv<PBF>(gamma, V * l + v);
            bev[v] = ldv<PBF>(beta,  V * l + v);
        }
    }

    for (int n = blockIdx.x * 4 + w; n < N_NODES; n += gridDim.x * 4) {
        const int b0 = rowptr[n], b1 = rowptr[n + 1];
        const int deg = b1 - b0;
        const float ad = adst[n * H + hd];

        // pass 1: online (max,sum) of softmax logits; edges strided over head group
        float m = -1e30f, s = 0.f;
        for (int j = b0 + slot; j < b1; j += LPH) {
            int sn = csr_src[j];
            float e = asr[sn * H + hd] + ad;
            e = e > 0.f ? e : 0.2f * e;
            float mn = fmaxf(m, e);
            s = s * __expf(m - mn) + __expf(e - mn);
            m = mn;
        }
        #pragma unroll
        for (int off = 1; off < LPH; off <<= 1) {
            float mo = __shfl_xor(m, off);
            float so = __shfl_xor(s, off);
            float mn = fmaxf(m, mo);
            s = s * __expf(m - mn) + so * __expf(mo - mn);
            m = mn;
        }
        const float inv_s = 1.f / s;

        float acc[V];
        #pragma unroll
        for (int v = 0; v < V; v++) acc[v] = 0.f;

        // pass 2: chunked register-staged alpha + vectorized gather
        for (int cbase = 0; cbase < deg; cbase += LPH) {
            const int nn = min(LPH, deg - cbase);
            int   sn_l = 0;
            float al_l = 0.f;
            if (slot < nn) {
                sn_l = csr_src[b0 + cbase + slot];
                float e = asr[sn_l * H + hd] + ad;
                e = e > 0.f ? e : 0.2f * e;
                al_l = __expf(e - m) * inv_s;
            }
            auto body = [&](int e) {
                int   src = lbase + e;
                int   sn  = __shfl(sn_l, src);
                float a   = __shfl(al_l, src);
                float xv[V];
                ldbf<V>(xp + (size_t)sn * CT + V * l, xv);
                #pragma unroll
                for (int v = 0; v < V; v++) acc[v] = fmaf(a, xv[v], acc[v]);
            };
            int e = 0;
            for (; e + 2 <= nn; e += 2) { body(e); body(e + 1); }
            for (; e < nn; e++) body(e);
        }
        #pragma unroll
        for (int v = 0; v < V; v++) acc[v] += bv[v];

        if constexpr (!LAST) {
            // LayerNorm over CT (wave-local) + ELU, write bf16
            float lsum = 0.f, lsq = 0.f;
            #pragma unroll
            for (int v = 0; v < V; v++) { lsum += acc[v]; lsq = fmaf(acc[v], acc[v], lsq); }
            #pragma unroll
            for (int off = 1; off < 64; off <<= 1) {
                lsum += __shfl_xor(lsum, off);
                lsq  += __shfl_xor(lsq,  off);
            }
            float mu  = lsum * (1.f / CT);
            float var = lsq  * (1.f / CT) - mu * mu;
            float rs  = rsqrtf(var + 1e-5f);
            unsigned short uo[V];
            #pragma unroll
            for (int v = 0; v < V; v++) {
                float y = (acc[v] - mu) * rs * gv[v] + bev[v];
                y = y > 0.f ? y : expm1f(y);
                uo[v] = f2u(y);
            }
            if constexpr (V == 4) {
                uint2 o;
                o.x = (unsigned int)uo[0] | ((unsigned int)uo[1] << 16);
                o.y = (unsigned int)uo[2] | ((unsigned int)uo[3] << 16);
                *(uint2*)((bf16*)outv + (size_t)n * CT + V * l) = o;
            } else {
                unsigned int o = (unsigned int)uo[0] | ((unsigned int)uo[1] << 16);
                *(unsigned int*)((bf16*)outv + (size_t)n * CT + V * l) = o;
            }
        } else {
            if constexpr (PBF) {
                unsigned int o = (unsigned int)f2u(acc[0]) | ((unsigned int)f2u(acc[1]) << 16);
                *(unsigned int*)((bf16*)outv + (size_t)n * CT + V * l) = o;
            } else {
                *(float2*)((float*)outv + (size_t)n * CT + V * l) = make_float2(acc[0], acc[1]);
            }
        }
    }
}

// --------------------------------- launcher --------------------------------
extern "C" void kernel_launch(void* const* d_in, const int* in_sizes, int n_in,
                              void* d_out, int out_size, void* d_ws, size_t ws_size,
                              hipStream_t stream) {
    const void* x   = d_in[0];
    const void* ei  = d_in[1];
    const void* W1  = d_in[2];
    const void* as1 = d_in[3];
    const void* ad1 = d_in[4];
    const void* b1  = d_in[5];
    const void* g1  = d_in[6];
    const void* be1 = d_in[7];
    const void* W2  = d_in[8];
    const void* as2 = d_in[9];
    const void* ad2 = d_in[10];
    const void* b2  = d_in[11];
    const void* g2  = d_in[12];
    const void* be2 = d_in[13];
    const void* W3  = d_in[14];
    const void* as3 = d_in[15];
    const void* ad3 = d_in[16];
    const void* b3  = d_in[17];

    char* ws = (char*)d_ws;
    bf16*  xp     = (bf16*)(ws);                // [N,256] bf16 = 25,600,000 B
    bf16*  hbuf   = (bf16*)(ws + 25600000);     // [N,256] bf16 = 25,600,000 B
    float* asr    = (float*)(ws + 51200000);
    float* adst   = (float*)(ws + 52000000);
    int*   counts = (int*)  (ws + 52800000);
    int*   scannd = (int*)  (ws + 53000000);
    int*   part   = (int*)  (ws + 53200000);
    int*   rowptr = (int*)  (ws + 53200256);
    int*   cursor = (int*)  (ws + 53400260);
    int*   csrsrc = (int*)  (ws + 53600260);
    int*   flags  = (int*)  (ws + 57000260);

    const int nb_scan = (N_NODES + SCAN_B - 1) / SCAN_B;
    const int NODEB   = (N_NODES + 3) / 4;      // 4 node-waves per 256-block

    k_detect<<<1, 64, 0, stream>>>((const unsigned int*)x, (const unsigned int*)ei, flags);

    k_zero<<<(N_NODES + 255) / 256, 256, 0, stream>>>(counts, N_NODES);
    k_hist<false><<<(E_TOT + 255) / 256, 256, 0, stream>>>(flags, ei, counts);
    k_hist<true ><<<(E_TOT + 255) / 256, 256, 0, stream>>>(flags, ei, counts);
    k_scan1<<<nb_scan, SCAN_B, 0, stream>>>(counts, scannd, part, N_NODES);
    k_scan2<<<1, 64, 0, stream>>>(part, nb_scan);
    k_scan3<<<(N_NODES + 255) / 256, 256, 0, stream>>>(counts, scannd, part, rowptr, cursor, N_NODES);
    k_scatter<false><<<(E_TOT + 255) / 256, 256, 0, stream>>>(flags, ei, cursor, csrsrc);
    k_scatter<true ><<<(E_TOT + 255) / 256, 256, 0, stream>>>(flags, ei, cursor, csrsrc);

    // ---- layer 1: in 128 -> xp [N,256], H=4, C=64, V=4
    k_gemm<128, 256, 128, false, false><<<2048, 256, 0, stream>>>(flags, x, W1, xp);
    k_gemm<128, 256, 128, true,  true ><<<2048, 256, 0, stream>>>(flags, x, W1, xp);
    k_attdots2<256, 4, 4, false><<<NODEB, 256, 0, stream>>>(flags, xp, as1, ad1, asr, adst);
    k_attdots2<256, 4, 4, true ><<<NODEB, 256, 0, stream>>>(flags, xp, as1, ad1, asr, adst);
    k_agg2<256, 4, 4, false, false><<<NODEB, 256, 0, stream>>>(flags, xp, asr, adst, rowptr, csrsrc, b1, g1, be1, hbuf);
    k_agg2<256, 4, 4, false, true ><<<NODEB, 256, 0, stream>>>(flags, xp, asr, adst, rowptr, csrsrc, b1, g1, be1, hbuf);

    // ---- layer 2: in 256 (bf16 hbuf) -> xp [N,128], H=2, C=64, V=2
    k_gemm<256, 128, 64, true, false><<<2048, 256, 0, stream>>>(flags, hbuf, W2, xp);
    k_gemm<256, 128, 64, true, true ><<<2048, 256, 0, stream>>>(flags, hbuf, W2, xp);
    k_attdots2<128, 2, 2, false><<<NODEB, 256, 0, stream>>>(flags, xp, as2, ad2, asr, adst);
    k_attdots2<128, 2, 2, true ><<<NODEB, 256, 0, stream>>>(flags, xp, as2, ad2, asr, adst);
    k_agg2<128, 2, 2, false, false><<<NODEB, 256, 0, stream>>>(flags, xp, asr, adst, rowptr, csrsrc, b2, g2, be2, hbuf);
    k_agg2<128, 2, 2, false, true ><<<NODEB, 256, 0, stream>>>(flags, xp, asr, adst, rowptr, csrsrc, b2, g2, be2, hbuf);

    // ---- layer 3: in 128 (bf16 hbuf) -> xp [N,128], H=1, C=128, V=2; write d_out
    k_gemm<128, 128, 128, true, false><<<2048, 256, 0, stream>>>(flags, hbuf, W3, xp);
    k_gemm<128, 128, 128, true, true ><<<2048, 256, 0, stream>>>(flags, hbuf, W3, xp);
    k_attdots2<128, 1, 2, false><<<NODEB, 256, 0, stream>>>(flags, xp, as3, ad3, asr, adst);
    k_attdots2<128, 1, 2, true ><<<NODEB, 256, 0, stream>>>(flags, xp, as3, ad3, asr, adst);
    k_agg2<128, 1, 2, true, false><<<NODEB, 256, 0, stream>>>(flags, xp, asr, adst, rowptr, csrsrc, b3, nullptr, nullptr, d_out);
    k_agg2<128, 1, 2, true, true ><<<NODEB, 256, 0, stream>>>(flags, xp, asr, adst, rowptr, csrsrc, b3, nullptr, nullptr, d_out);
}

// Round 5
// 402.568 us; speedup vs baseline: 2.3934x; 1.4718x over previous
//
#include <hip/hip_runtime.h>
#include <hip/hip_bf16.h>
#include <math.h>

#define N_NODES 50000
#define N_EDGES 800000
#define E_TOT   850000   // N_EDGES + N_NODES self-loops
#define SCAN_B  1024

typedef __hip_bfloat16 bf16;
typedef __attribute__((ext_vector_type(8))) short short8v;   // 8 bf16 (4 VGPR)
typedef __attribute__((ext_vector_type(4))) float float4v;   // MFMA acc

static __device__ __forceinline__ float u2f(unsigned short u) {
    return __uint_as_float(((unsigned int)u) << 16);
}
static __device__ __forceinline__ unsigned short f2u(float f) {   // RNE f32->bf16
    unsigned int u = __float_as_uint(f);
    return (unsigned short)((u + 0x7FFFu + ((u >> 16) & 1u)) >> 16);
}

// load a float from an input buffer whose device dtype is bf16 (BF=true) or fp32
template<bool BF>
static __device__ __forceinline__ float ldv(const void* p, int i) {
    if constexpr (BF)
        return u2f(((const unsigned short*)p)[i]);
    else
        return ((const float*)p)[i];
}

// load V consecutive bf16 (vectorized) and convert to float
template<int V>
static __device__ __forceinline__ void ldbf(const bf16* p, float* out) {
    if constexpr (V == 4) {
        ushort4 u = *(const ushort4*)p;
        out[0] = u2f(u.x); out[1] = u2f(u.y); out[2] = u2f(u.z); out[3] = u2f(u.w);
    } else {
        ushort2 u = *(const ushort2*)p;
        out[0] = u2f(u.x); out[1] = u2f(u.y);
    }
}

// ------------------------- dtype detection (device) ------------------------
__global__ void k_detect(const unsigned int* __restrict__ x32,
                         const unsigned int* __restrict__ ei32,
                         int* __restrict__ flags) {
    if (threadIdx.x == 0 && blockIdx.x == 0) {
        int cnt = 0;
        for (int i = 0; i < 256; i++) {
            unsigned int e = (x32[i] >> 7) & 0xFF;
            cnt += (e >= 90 && e <= 140) ? 1 : 0;
        }
        flags[0] = (cnt >= 128) ? 1 : 0;
        int z = 0;
        for (int i = 0; i < 64; i++) z += (ei32[2 * i + 1] == 0) ? 1 : 0;
        flags[1] = (z >= 48) ? 1 : 0;
    }
}

// ------------------------------ CSR build ---------------------------------
__global__ void k_zero(int* __restrict__ p, int n) {
    int i = blockIdx.x * blockDim.x + threadIdx.x;
    if (i < n) p[i] = 0;
}

template<bool I64>
__global__ void k_hist(const int* __restrict__ flags, const void* __restrict__ ei,
                       int* __restrict__ counts) {
    if ((flags[1] != 0) != I64) return;
    int i = blockIdx.x * blockDim.x + threadIdx.x;
    if (i >= E_TOT) return;
    int d;
    if (i < N_EDGES)
        d = I64 ? (int)((const long long*)ei)[N_EDGES + i] : ((const int*)ei)[N_EDGES + i];
    else
        d = i - N_EDGES;
    atomicAdd(&counts[d], 1);
}

__global__ void k_scan1(const int* __restrict__ counts, int* __restrict__ scanned,
                        int* __restrict__ partial, int n) {
    __shared__ int sh[SCAN_B];
    int i = blockIdx.x * SCAN_B + threadIdx.x;
    sh[threadIdx.x] = (i < n) ? counts[i] : 0;
    __syncthreads();
    for (int off = 1; off < SCAN_B; off <<= 1) {
        int t = (threadIdx.x >= off) ? sh[threadIdx.x - off] : 0;
        __syncthreads();
        sh[threadIdx.x] += t;
        __syncthreads();
    }
    if (i < n) scanned[i] = sh[threadIdx.x];
    if (threadIdx.x == SCAN_B - 1) partial[blockIdx.x] = sh[SCAN_B - 1];
}

__global__ void k_scan2(int* __restrict__ partial, int nb) {
    if (threadIdx.x == 0 && blockIdx.x == 0) {
        int acc = 0;
        for (int b = 0; b < nb; b++) { int t = partial[b]; partial[b] = acc; acc += t; }
    }
}

__global__ void k_scan3(const int* __restrict__ counts, const int* __restrict__ scanned,
                        const int* __restrict__ partial, int* __restrict__ rowptr,
                        int* __restrict__ cursor, int n) {
    int i = blockIdx.x * blockDim.x + threadIdx.x;
    if (i >= n) return;
    int incl = scanned[i] + partial[i / SCAN_B];
    rowptr[i + 1] = incl;
    cursor[i]     = incl - counts[i];
    if (i == 0) rowptr[0] = 0;
}

template<bool I64>
__global__ void k_scatter(const int* __restrict__ flags, const void* __restrict__ ei,
                          int* __restrict__ cursor, int* __restrict__ csr_src) {
    if ((flags[1] != 0) != I64) return;
    int i = blockIdx.x * blockDim.x + threadIdx.x;
    if (i >= E_TOT) return;
    int s, d;
    if (i < N_EDGES) {
        if constexpr (I64) {
            s = (int)((const long long*)ei)[i];
            d = (int)((const long long*)ei)[N_EDGES + i];
        } else {
            s = ((const int*)ei)[i];
            d = ((const int*)ei)[N_EDGES + i];
        }
    } else {
        s = d = i - N_EDGES;
    }
    int pos = atomicAdd(&cursor[d], 1);
    csr_src[pos] = s;
}

// ----------------------- input canonicalization ---------------------------
// x (per-flag dtype) -> xb bf16
template<bool XBF>
__global__ void k_prepx(const int* __restrict__ flags, const void* __restrict__ x,
                        bf16* __restrict__ xb, int n4) {
    if ((flags[0] != 0) != XBF) return;
    int i = blockIdx.x * blockDim.x + threadIdx.x;
    if (i >= n4) return;
    if constexpr (XBF) {
        ((ushort4*)xb)[i] = ((const ushort4*)x)[i];
    } else {
        float4 f = ((const float4*)x)[i];
        ushort4 u;
        u.x = f2u(f.x); u.y = f2u(f.y); u.z = f2u(f.z); u.w = f2u(f.w);
        ((ushort4*)xb)[i] = u;
    }
}

// W [K][NT] (per-flag dtype) -> Wt [NT][K] bf16
template<int K, int NT, bool PBF>
__global__ void k_prepw(const int* __restrict__ flags, const void* __restrict__ W,
                        bf16* __restrict__ Wt) {
    if ((flags[0] != 0) != PBF) return;
    int i = blockIdx.x * blockDim.x + threadIdx.x;
    if (i >= K * NT) return;
    int k = i / NT, c = i - k * NT;
    Wt[c * K + k] = __float2bfloat16(ldv<PBF>(W, i));
}

// --------------------------- MFMA GEMM: xp = A @ W -------------------------
// A [M][K] bf16 row-major; Wt [NT][K] bf16 (W transposed); xp [M][NT] bf16.
// Per-wave: owns SPW 16-col slices, B-frags resident in registers, loops over
// 16-row M-tiles. mfma_f32_16x16x32_bf16:
//   A frag: row=lane&15, k=(lane>>4)*8+e  (contiguous 16B per lane)
//   B frag: col=lane&15, k=(lane>>4)*8+e  (contiguous 16B per lane from Wt)
//   D frag: col=lane&15, row=(lane>>4)*4+r (verified m89/m91)
template<int K, int NT, int SPW>
__global__ __launch_bounds__(256) void k_gemm_mfma(const bf16* __restrict__ A,
                                                   const bf16* __restrict__ Wt,
                                                   bf16* __restrict__ xp) {
    constexpr int KF     = K / 32;            // mfma K-steps
    constexpr int NSG    = NT / (16 * SPW);   // slice groups
    constexpr int NTILES = N_NODES / 16;      // 3125 (exact)
    const int l    = threadIdx.x & 63;
    const int wid  = blockIdx.x * 4 + (threadIdx.x >> 6);
    const int sg   = wid % NSG;
    const int wpg  = (gridDim.x * 4) / NSG;
    const int t0   = wid / NSG;
    const int r16  = l & 15;
    const int kgrp = (l >> 4) * 8;

    short8v b[SPW][KF];
    #pragma unroll
    for (int s = 0; s < SPW; s++) {
        const int col = (sg * SPW + s) * 16 + r16;
        #pragma unroll
        for (int kf = 0; kf < KF; kf++)
            b[s][kf] = *(const short8v*)(Wt + (size_t)col * K + kf * 32 + kgrp);
    }

    for (int t = t0; t < NTILES; t += wpg) {
        const int m0 = t * 16;
        short8v a[KF];
        #pragma unroll
        for (int kf = 0; kf < KF; kf++)
            a[kf] = *(const short8v*)(A + (size_t)(m0 + r16) * K + kf * 32 + kgrp);
        float4v acc[SPW] = {};
        #pragma unroll
        for (int kf = 0; kf < KF; kf++)
            #pragma unroll
            for (int s = 0; s < SPW; s++)
                acc[s] = __builtin_amdgcn_mfma_f32_16x16x32_bf16(a[kf], b[s][kf], acc[s], 0, 0, 0);
        const int rbase = m0 + (l >> 4) * 4;
        #pragma unroll
        for (int s = 0; s < SPW; s++) {
            const int col = (sg * SPW + s) * 16 + r16;
            #pragma unroll
            for (int r = 0; r < 4; r++)
                xp[(size_t)(rbase + r) * NT + col] = __float2bfloat16(acc[s][r]);
        }
    }
}

// ---------------------- per-node attention dot products --------------------
template<int CT, int H, int V, bool PBF>
__global__ __launch_bounds__(256) void k_attdots2(const int* __restrict__ flags,
                                                  const bf16* __restrict__ xp,
                                                  const void* __restrict__ att_s,
                                                  const void* __restrict__ att_d,
                                                  float* __restrict__ asr,
                                                  float* __restrict__ adst) {
    if ((flags[0] != 0) != PBF) return;
    constexpr int LPH = (CT / H) / V;       // lanes per head group
    const int l    = threadIdx.x & 63;
    const int w    = threadIdx.x >> 6;
    const int hd   = l / LPH;
    const int slot = l & (LPH - 1);
    float ws[V], wd[V];
    #pragma unroll
    for (int v = 0; v < V; v++) {
        ws[v] = ldv<PBF>(att_s, V * l + v);
        wd[v] = ldv<PBF>(att_d, V * l + v);
    }
    for (int n = blockIdx.x * 4 + w; n < N_NODES; n += gridDim.x * 4) {
        float xv[V];
        ldbf<V>(xp + (size_t)n * CT + V * l, xv);
        float s1 = 0.f, s2 = 0.f;
        #pragma unroll
        for (int v = 0; v < V; v++) { s1 = fmaf(xv[v], ws[v], s1); s2 = fmaf(xv[v], wd[v], s2); }
        #pragma unroll
        for (int off = 1; off < LPH; off <<= 1) {
            s1 += __shfl_xor(s1, off);
            s2 += __shfl_xor(s2, off);
        }
        if (slot == 0) {
            asr[n * H + hd]  = s1;
            adst[n * H + hd] = s2;
        }
    }
}

// -------- fused edge-softmax + aggregation + bias (+ LayerNorm + ELU) ------
template<int CT, int H, int V, bool LAST, bool PBF>
__global__ __launch_bounds__(256) void k_agg2(const int* __restrict__ flags,
                                              const bf16* __restrict__ xp,
                                              const float* __restrict__ asr,
                                              const float* __restrict__ adst,
                                              const int* __restrict__ rowptr,
                                              const int* __restrict__ csr_src,
                                              const void* __restrict__ bias,
                                              const void* __restrict__ gamma,
                                              const void* __restrict__ beta,
                                              void* __restrict__ outv) {
    if ((flags[0] != 0) != PBF) return;
    constexpr int C   = CT / H;
    constexpr int LPH = C / V;              // lanes per head group == edge chunk
    const int l     = threadIdx.x & 63;
    const int w     = threadIdx.x >> 6;
    const int hd    = l / LPH;
    const int slot  = l & (LPH - 1);
    const int lbase = l - slot;

    float bv[V];
    #pragma unroll
    for (int v = 0; v < V; v++) bv[v] = ldv<PBF>(bias, V * l + v);
    float gv[V], bev[V];
    if constexpr (!LAST) {
        #pragma unroll
        for (int v = 0; v < V; v++) {
            gv[v]  = ldv<PBF>(gamma, V * l + v);
            bev[v] = ldv<PBF>(beta,  V * l + v);
        }
    }

    for (int n = blockIdx.x * 4 + w; n < N_NODES; n += gridDim.x * 4) {
        const int b0 = rowptr[n], b1 = rowptr[n + 1];
        const int deg = b1 - b0;
        const float ad = adst[n * H + hd];

        float m = -1e30f, s = 0.f;
        for (int j = b0 + slot; j < b1; j += LPH) {
            int sn = csr_src[j];
            float e = asr[sn * H + hd] + ad;
            e = e > 0.f ? e : 0.2f * e;
            float mn = fmaxf(m, e);
            s = s * __expf(m - mn) + __expf(e - mn);
            m = mn;
        }
        #pragma unroll
        for (int off = 1; off < LPH; off <<= 1) {
            float mo = __shfl_xor(m, off);
            float so = __shfl_xor(s, off);
            float mn = fmaxf(m, mo);
            s = s * __expf(m - mn) + so * __expf(mo - mn);
            m = mn;
        }
        const float inv_s = 1.f / s;

        float acc[V];
        #pragma unroll
        for (int v = 0; v < V; v++) acc[v] = 0.f;

        for (int cbase = 0; cbase < deg; cbase += LPH) {
            const int nn = min(LPH, deg - cbase);
            int   sn_l = 0;
            float al_l = 0.f;
            if (slot < nn) {
                sn_l = csr_src[b0 + cbase + slot];
                float e = asr[sn_l * H + hd] + ad;
                e = e > 0.f ? e : 0.2f * e;
                al_l = __expf(e - m) * inv_s;
            }
            auto body = [&](int e) {
                int   src = lbase + e;
                int   sn  = __shfl(sn_l, src);
                float a   = __shfl(al_l, src);
                float xv[V];
                ldbf<V>(xp + (size_t)sn * CT + V * l, xv);
                #pragma unroll
                for (int v = 0; v < V; v++) acc[v] = fmaf(a, xv[v], acc[v]);
            };
            int e = 0;
            for (; e + 2 <= nn; e += 2) { body(e); body(e + 1); }
            for (; e < nn; e++) body(e);
        }
        #pragma unroll
        for (int v = 0; v < V; v++) acc[v] += bv[v];

        if constexpr (!LAST) {
            float lsum = 0.f, lsq = 0.f;
            #pragma unroll
            for (int v = 0; v < V; v++) { lsum += acc[v]; lsq = fmaf(acc[v], acc[v], lsq); }
            #pragma unroll
            for (int off = 1; off < 64; off <<= 1) {
                lsum += __shfl_xor(lsum, off);
                lsq  += __shfl_xor(lsq,  off);
            }
            float mu  = lsum * (1.f / CT);
            float var = lsq  * (1.f / CT) - mu * mu;
            float rs  = rsqrtf(var + 1e-5f);
            unsigned short uo[V];
            #pragma unroll
            for (int v = 0; v < V; v++) {
                float y = (acc[v] - mu) * rs * gv[v] + bev[v];
                y = y > 0.f ? y : expm1f(y);
                uo[v] = f2u(y);
            }
            if constexpr (V == 4) {
                uint2 o;
                o.x = (unsigned int)uo[0] | ((unsigned int)uo[1] << 16);
                o.y = (unsigned int)uo[2] | ((unsigned int)uo[3] << 16);
                *(uint2*)((bf16*)outv + (size_t)n * CT + V * l) = o;
            } else {
                unsigned int o = (unsigned int)uo[0] | ((unsigned int)uo[1] << 16);
                *(unsigned int*)((bf16*)outv + (size_t)n * CT + V * l) = o;
            }
        } else {
            if constexpr (PBF) {
                unsigned int o = (unsigned int)f2u(acc[0]) | ((unsigned int)f2u(acc[1]) << 16);
                *(unsigned int*)((bf16*)outv + (size_t)n * CT + V * l) = o;
            } else {
                *(float2*)((float*)outv + (size_t)n * CT + V * l) = make_float2(acc[0], acc[1]);
            }
        }
    }
}

// --------------------------------- launcher --------------------------------
extern "C" void kernel_launch(void* const* d_in, const int* in_sizes, int n_in,
                              void* d_out, int out_size, void* d_ws, size_t ws_size,
                              hipStream_t stream) {
    const void* x   = d_in[0];
    const void* ei  = d_in[1];
    const void* W1  = d_in[2];
    const void* as1 = d_in[3];
    const void* ad1 = d_in[4];
    const void* b1  = d_in[5];
    const void* g1  = d_in[6];
    const void* be1 = d_in[7];
    const void* W2  = d_in[8];
    const void* as2 = d_in[9];
    const void* ad2 = d_in[10];
    const void* b2  = d_in[11];
    const void* g2  = d_in[12];
    const void* be2 = d_in[13];
    const void* W3  = d_in[14];
    const void* as3 = d_in[15];
    const void* ad3 = d_in[16];
    const void* b3  = d_in[17];

    char* ws = (char*)d_ws;
    bf16*  xp     = (bf16*)(ws);                // [N,256] bf16 = 25,600,000 B
    bf16*  hbuf   = (bf16*)(ws + 25600000);     // [N,256] bf16; also hosts xb (layer-1 input)
    float* asr    = (float*)(ws + 51200000);
    float* adst   = (float*)(ws + 52000000);
    int*   counts = (int*)  (ws + 52800000);
    int*   scannd = (int*)  (ws + 53000000);
    int*   part   = (int*)  (ws + 53200000);
    int*   rowptr = (int*)  (ws + 53200256);
    int*   cursor = (int*)  (ws + 53400260);
    int*   csrsrc = (int*)  (ws + 53600260);
    int*   flags  = (int*)  (ws + 57000260);
    bf16*  Wt1    = (bf16*)(ws + 57000320);     // [256][128] bf16 = 65,536 B
    bf16*  Wt2    = (bf16*)(ws + 57065856);     // [128][256] bf16 = 65,536 B
    bf16*  Wt3    = (bf16*)(ws + 57131392);     // [128][128] bf16 = 32,768 B

    bf16* xb = hbuf;   // x canonicalized to bf16; dead before agg1 writes hbuf

    const int nb_scan = (N_NODES + SCAN_B - 1) / SCAN_B;
    const int NODEB   = (N_NODES + 3) / 4;      // 4 node-waves per 256-block

    k_detect<<<1, 64, 0, stream>>>((const unsigned int*)x, (const unsigned int*)ei, flags);

    // CSR build
    k_zero<<<(N_NODES + 255) / 256, 256, 0, stream>>>(counts, N_NODES);
    k_hist<false><<<(E_TOT + 255) / 256, 256, 0, stream>>>(flags, ei, counts);
    k_hist<true ><<<(E_TOT + 255) / 256, 256, 0, stream>>>(flags, ei, counts);
    k_scan1<<<nb_scan, SCAN_B, 0, stream>>>(counts, scannd, part, N_NODES);
    k_scan2<<<1, 64, 0, stream>>>(part, nb_scan);
    k_scan3<<<(N_NODES + 255) / 256, 256, 0, stream>>>(counts, scannd, part, rowptr, cursor, N_NODES);
    k_scatter<false><<<(E_TOT + 255) / 256, 256, 0, stream>>>(flags, ei, cursor, csrsrc);
    k_scatter<true ><<<(E_TOT + 255) / 256, 256, 0, stream>>>(flags, ei, cursor, csrsrc);

    // canonicalize inputs to bf16
    const int n4 = N_NODES * 128 / 4;
    k_prepx<false><<<(n4 + 255) / 256, 256, 0, stream>>>(flags, x, xb, n4);
    k_prepx<true ><<<(n4 + 255) / 256, 256, 0, stream>>>(flags, x, xb, n4);
    k_prepw<128, 256, false><<<128, 256, 0, stream>>>(flags, W1, Wt1);
    k_prepw<128, 256, true ><<<128, 256, 0, stream>>>(flags, W1, Wt1);
    k_prepw<256, 128, false><<<128, 256, 0, stream>>>(flags, W2, Wt2);
    k_prepw<256, 128, true ><<<128, 256, 0, stream>>>(flags, W2, Wt2);
    k_prepw<128, 128, false><<<64, 256, 0, stream>>>(flags, W3, Wt3);
    k_prepw<128, 128, true ><<<64, 256, 0, stream>>>(flags, W3, Wt3);

    // ---- layer 1: in 128 -> xp [N,256], H=4, C=64, V=4
    k_gemm_mfma<128, 256, 4><<<512, 256, 0, stream>>>(xb, Wt1, xp);
    k_attdots2<256, 4, 4, false><<<NODEB, 256, 0, stream>>>(flags, xp, as1, ad1, asr, adst);
    k_attdots2<256, 4, 4, true ><<<NODEB, 256, 0, stream>>>(flags, xp, as1, ad1, asr, adst);
    k_agg2<256, 4, 4, false, false><<<NODEB, 256, 0, stream>>>(flags, xp, asr, adst, rowptr, csrsrc, b1, g1, be1, hbuf);
    k_agg2<256, 4, 4, false, true ><<<NODEB, 256, 0, stream>>>(flags, xp, asr, adst, rowptr, csrsrc, b1, g1, be1, hbuf);

    // ---- layer 2: in 256 (bf16 hbuf) -> xp [N,128], H=2, C=64, V=2
    k_gemm_mfma<256, 128, 2><<<512, 256, 0, stream>>>(hbuf, Wt2, xp);
    k_attdots2<128, 2, 2, false><<<NODEB, 256, 0, stream>>>(flags, xp, as2, ad2, asr, adst);
    k_attdots2<128, 2, 2, true ><<<NODEB, 256, 0, stream>>>(flags, xp, as2, ad2, asr, adst);
    k_agg2<128, 2, 2, false, false><<<NODEB, 256, 0, stream>>>(flags, xp, asr, adst, rowptr, csrsrc, b2, g2, be2, hbuf);
    k_agg2<128, 2, 2, false, true ><<<NODEB, 256, 0, stream>>>(flags, xp, asr, adst, rowptr, csrsrc, b2, g2, be2, hbuf);

    // ---- layer 3: in 128 (bf16 hbuf) -> xp [N,128], H=1, C=128, V=2; write d_out
    k_gemm_mfma<128, 128, 2><<<512, 256, 0, stream>>>(hbuf, Wt3, xp);
    k_attdots2<128, 1, 2, false><<<NODEB, 256, 0, stream>>>(flags, xp, as3, ad3, asr, adst);
    k_attdots2<128, 1, 2, true ><<<NODEB, 256, 0, stream>>>(flags, xp, as3, ad3, asr, adst);
    k_agg2<128, 1, 2, true, false><<<NODEB, 256, 0, stream>>>(flags, xp, asr, adst, rowptr, csrsrc, b3, nullptr, nullptr, d_out);
    k_agg2<128, 1, 2, true, true ><<<NODEB, 256, 0, stream>>>(flags, xp, asr, adst, rowptr, csrsrc, b3, nullptr, nullptr, d_out);
}

// Round 6
// 354.837 us; speedup vs baseline: 2.7153x; 1.1345x over previous
//
#include <hip/hip_runtime.h>
#include <hip/hip_bf16.h>
#include <math.h>

#define N_NODES 50000
#define N_EDGES 800000
#define E_TOT   850000   // N_EDGES + N_NODES self-loops
#define SCAN_B  1024

typedef __hip_bfloat16 bf16;
typedef __attribute__((ext_vector_type(8))) short short8v;   // 8 bf16 (4 VGPR)
typedef __attribute__((ext_vector_type(4))) float float4v;   // MFMA acc

static __device__ __forceinline__ float u2f(unsigned short u) {
    return __uint_as_float(((unsigned int)u) << 16);
}
static __device__ __forceinline__ unsigned short f2u(float f) {   // RNE f32->bf16
    unsigned int u = __float_as_uint(f);
    return (unsigned short)((u + 0x7FFFu + ((u >> 16) & 1u)) >> 16);
}

template<bool BF>
static __device__ __forceinline__ float ldv(const void* p, int i) {
    if constexpr (BF)
        return u2f(((const unsigned short*)p)[i]);
    else
        return ((const float*)p)[i];
}

// ------------------------- dtype detection (device) ------------------------
__global__ void k_detect(const unsigned int* __restrict__ x32,
                         const unsigned int* __restrict__ ei32,
                         int* __restrict__ flags) {
    if (threadIdx.x == 0 && blockIdx.x == 0) {
        int cnt = 0;
        for (int i = 0; i < 256; i++) {
            unsigned int e = (x32[i] >> 7) & 0xFF;
            cnt += (e >= 90 && e <= 140) ? 1 : 0;
        }
        flags[0] = (cnt >= 128) ? 1 : 0;
        int z = 0;
        for (int i = 0; i < 64; i++) z += (ei32[2 * i + 1] == 0) ? 1 : 0;
        flags[1] = (z >= 48) ? 1 : 0;
    }
}

// ------------------------------ CSR build ---------------------------------
__global__ void k_zero(int* __restrict__ p, int n) {
    int i = blockIdx.x * blockDim.x + threadIdx.x;
    if (i < n) p[i] = 0;
}

template<bool I64>
__global__ void k_hist(const int* __restrict__ flags, const void* __restrict__ ei,
                       int* __restrict__ counts) {
    if ((flags[1] != 0) != I64) return;
    int i = blockIdx.x * blockDim.x + threadIdx.x;
    if (i >= E_TOT) return;
    int d;
    if (i < N_EDGES)
        d = I64 ? (int)((const long long*)ei)[N_EDGES + i] : ((const int*)ei)[N_EDGES + i];
    else
        d = i - N_EDGES;
    atomicAdd(&counts[d], 1);
}

__global__ void k_scan1(const int* __restrict__ counts, int* __restrict__ scanned,
                        int* __restrict__ partial, int n) {
    __shared__ int sh[SCAN_B];
    int i = blockIdx.x * SCAN_B + threadIdx.x;
    sh[threadIdx.x] = (i < n) ? counts[i] : 0;
    __syncthreads();
    for (int off = 1; off < SCAN_B; off <<= 1) {
        int t = (threadIdx.x >= off) ? sh[threadIdx.x - off] : 0;
        __syncthreads();
        sh[threadIdx.x] += t;
        __syncthreads();
    }
    if (i < n) scanned[i] = sh[threadIdx.x];
    if (threadIdx.x == SCAN_B - 1) partial[blockIdx.x] = sh[SCAN_B - 1];
}

__global__ void k_scan2(int* __restrict__ partial, int nb) {
    if (threadIdx.x == 0 && blockIdx.x == 0) {
        int acc = 0;
        for (int b = 0; b < nb; b++) { int t = partial[b]; partial[b] = acc; acc += t; }
    }
}

__global__ void k_scan3(const int* __restrict__ counts, const int* __restrict__ scanned,
                        const int* __restrict__ partial, int* __restrict__ rowptr,
                        int* __restrict__ cursor, int n) {
    int i = blockIdx.x * blockDim.x + threadIdx.x;
    if (i >= n) return;
    int incl = scanned[i] + partial[i / SCAN_B];
    rowptr[i + 1] = incl;
    cursor[i]     = incl - counts[i];
    if (i == 0) rowptr[0] = 0;
}

template<bool I64>
__global__ void k_scatter(const int* __restrict__ flags, const void* __restrict__ ei,
                          int* __restrict__ cursor, int* __restrict__ csr_src) {
    if ((flags[1] != 0) != I64) return;
    int i = blockIdx.x * blockDim.x + threadIdx.x;
    if (i >= E_TOT) return;
    int s, d;
    if (i < N_EDGES) {
        if constexpr (I64) {
            s = (int)((const long long*)ei)[i];
            d = (int)((const long long*)ei)[N_EDGES + i];
        } else {
            s = ((const int*)ei)[i];
            d = ((const int*)ei)[N_EDGES + i];
        }
    } else {
        s = d = i - N_EDGES;
    }
    int pos = atomicAdd(&cursor[d], 1);
    csr_src[pos] = s;
}

// ----------------------- input canonicalization ---------------------------
template<bool XBF>
__global__ void k_prepx(const int* __restrict__ flags, const void* __restrict__ x,
                        bf16* __restrict__ xb, int n4) {
    if ((flags[0] != 0) != XBF) return;
    int i = blockIdx.x * blockDim.x + threadIdx.x;
    if (i >= n4) return;
    if constexpr (XBF) {
        ((ushort4*)xb)[i] = ((const ushort4*)x)[i];
    } else {
        float4 f = ((const float4*)x)[i];
        ushort4 u;
        u.x = f2u(f.x); u.y = f2u(f.y); u.z = f2u(f.z); u.w = f2u(f.w);
        ((ushort4*)xb)[i] = u;
    }
}

template<int K, int NT, bool PBF>
__global__ void k_prepw(const int* __restrict__ flags, const void* __restrict__ W,
                        bf16* __restrict__ Wt) {
    if ((flags[0] != 0) != PBF) return;
    int i = blockIdx.x * blockDim.x + threadIdx.x;
    if (i >= K * NT) return;
    int k = i / NT, c = i - k * NT;
    Wt[c * K + k] = __float2bfloat16(ldv<PBF>(W, i));
}

// small params -> canonical fp32 block
struct PrepArgs { const void* src[13]; int off[13]; int len[13]; };

template<bool PBF>
__global__ void k_prep_small(const int* __restrict__ flags, PrepArgs a,
                             float* __restrict__ par) {
    if ((flags[0] != 0) != PBF) return;
    for (int seg = blockIdx.x; seg < 13; seg += gridDim.x)
        for (int i = threadIdx.x; i < a.len[seg]; i += blockDim.x)
            par[a.off[seg] + i] = ldv<PBF>(a.src[seg], i);
}

// ------------- MFMA GEMM (swapped operands) + fused attention dots ---------
// A [M][K] bf16; Wt [NT][K] bf16; xp [M][NT] bf16.
// mfma(b_frag, a_frag): D'[ch][node]; lane holds node=m0+(l&15),
// ch = cs + (l>>4)*4 + r  -> 8B packed stores + cheap per-node dot reduce.
template<int K, int NT, int SPW, int H>
__global__ __launch_bounds__(256) void k_gemm_mfma2(const bf16* __restrict__ A,
                                                    const bf16* __restrict__ Wt,
                                                    bf16* __restrict__ xp,
                                                    const float* __restrict__ att_s,
                                                    const float* __restrict__ att_d,
                                                    float* __restrict__ asr,
                                                    float* __restrict__ adst) {
    constexpr int KF     = K / 32;
    constexpr int NSG    = NT / (16 * SPW);
    constexpr int NTILES = N_NODES / 16;
    constexpr int C      = NT / H;
    const int l    = threadIdx.x & 63;
    const int wid  = blockIdx.x * 4 + (threadIdx.x >> 6);
    const int sg   = wid % NSG;
    const int wpg  = (gridDim.x * 4) / NSG;
    const int t0   = wid / NSG;
    const int r16  = l & 15;
    const int kgrp = (l >> 4) * 8;
    const int head = (sg * SPW * 16) / C;   // wave spans a single head (verified per layer)

    short8v b[SPW][KF];
    float as_r[SPW][4], ad_r[SPW][4];
    #pragma unroll
    for (int s = 0; s < SPW; s++) {
        const int cs  = (sg * SPW + s) * 16;
        const int col = cs + r16;
        #pragma unroll
        for (int kf = 0; kf < KF; kf++)
            b[s][kf] = *(const short8v*)(Wt + (size_t)col * K + kf * 32 + kgrp);
        #pragma unroll
        for (int r = 0; r < 4; r++) {
            const int ch = cs + (l >> 4) * 4 + r;
            as_r[s][r] = att_s[ch];
            ad_r[s][r] = att_d[ch];
        }
    }

    for (int t = t0; t < NTILES; t += wpg) {
        const int m0 = t * 16;
        short8v a[KF];
        #pragma unroll
        for (int kf = 0; kf < KF; kf++)
            a[kf] = *(const short8v*)(A + (size_t)(m0 + r16) * K + kf * 32 + kgrp);
        float4v acc[SPW] = {};
        #pragma unroll
        for (int kf = 0; kf < KF; kf++)
            #pragma unroll
            for (int s = 0; s < SPW; s++)
                acc[s] = __builtin_amdgcn_mfma_f32_16x16x32_bf16(b[s][kf], a[kf], acc[s], 0, 0, 0);

        // fused attention dots: per-node partial over this wave's channels
        float pa = 0.f, pd = 0.f;
        #pragma unroll
        for (int s = 0; s < SPW; s++)
            #pragma unroll
            for (int r = 0; r < 4; r++) {
                pa = fmaf(acc[s][r], as_r[s][r], pa);
                pd = fmaf(acc[s][r], ad_r[s][r], pd);
            }
        pa += __shfl_xor(pa, 16); pa += __shfl_xor(pa, 32);
        pd += __shfl_xor(pd, 16); pd += __shfl_xor(pd, 32);
        if (l < 16) {
            atomicAdd(&asr [(size_t)(m0 + l) * H + head], pa);
            atomicAdd(&adst[(size_t)(m0 + l) * H + head], pd);
        }

        // packed 8B stores: node = m0+r16, 4 consecutive channels
        const int node = m0 + r16;
        #pragma unroll
        for (int s = 0; s < SPW; s++) {
            const int ch = (sg * SPW + s) * 16 + (l >> 4) * 4;
            uint2 o;
            o.x = (unsigned int)f2u(acc[s][0]) | ((unsigned int)f2u(acc[s][1]) << 16);
            o.y = (unsigned int)f2u(acc[s][2]) | ((unsigned int)f2u(acc[s][3]) << 16);
            *(uint2*)(xp + (size_t)node * NT + ch) = o;
        }
    }
}

// -------- fused edge-softmax + aggregation + bias (+ LayerNorm + ELU) ------
// NPW=2 nodes per wave (half-wave each), V channels/lane, 4-edge gather groups.
template<int ND>
static __device__ __forceinline__ void gacc(const unsigned int* __restrict__ xpd,
                                            int off, float a, float* __restrict__ acc) {
    unsigned int d[ND];
    if constexpr (ND == 4) {
        uint4 t = *(const uint4*)(xpd + off);
        d[0] = t.x; d[1] = t.y; d[2] = t.z; d[3] = t.w;
    } else {
        uint2 t = *(const uint2*)(xpd + off);
        d[0] = t.x; d[1] = t.y;
    }
    #pragma unroll
    for (int k = 0; k < ND; k++) {
        acc[2 * k]     = fmaf(a, __uint_as_float(d[k] << 16),         acc[2 * k]);
        acc[2 * k + 1] = fmaf(a, __uint_as_float(d[k] & 0xffff0000u), acc[2 * k + 1]);
    }
}

template<int CT, int H, bool LAST, bool OBF>
__global__ __launch_bounds__(256) void k_agg3(const int* __restrict__ flags,
                                              const bf16* __restrict__ xp,
                                              const float* __restrict__ asr,
                                              const float* __restrict__ adst,
                                              const int* __restrict__ rowptr,
                                              const int* __restrict__ csr_src,
                                              const float* __restrict__ bias,
                                              const float* __restrict__ gamma,
                                              const float* __restrict__ beta,
                                              void* __restrict__ outv) {
    if constexpr (LAST) { if ((flags[0] != 0) != OBF) return; }
    constexpr int NPW = 2;
    constexpr int LPN = 64 / NPW;     // 32 lanes per node
    constexpr int V   = CT / LPN;     // 4 or 8 channels per lane
    constexpr int C   = CT / H;
    constexpr int LPH = C / V;        // lanes per head group (8/16/32), mult of 4
    constexpr int ND  = V / 2;        // dwords gathered per lane
    constexpr int STR = CT / 2;       // xp row stride in dwords
    const int l     = threadIdx.x & 63;
    const int w     = threadIdx.x >> 6;
    const int half  = l / LPN;
    const int li    = l - half * LPN;
    const int hd    = li / LPH;
    const int slot  = li & (LPH - 1);
    const int lbase = half * LPN + hd * LPH;
    const int coff  = ND * li;        // lane's dword offset within a row

    float bv[V], gv[V], bev[V];
    #pragma unroll
    for (int v = 0; v < V; v++) bv[v] = bias[V * li + v];
    if constexpr (!LAST) {
        #pragma unroll
        for (int v = 0; v < V; v++) {
            gv[v]  = gamma[V * li + v];
            bev[v] = beta [V * li + v];
        }
    }
    const unsigned int* xpd = (const unsigned int*)xp;

    for (int n0 = blockIdx.x * 4 + w; n0 * NPW < N_NODES; n0 += gridDim.x * 4) {
        const int n  = n0 * NPW + half;                 // < N_NODES by grid sizing
        const int b0 = rowptr[n], b1 = rowptr[n + 1];
        const int deg = b1 - b0;
        const float ad = adst[n * H + hd];

        // pass 1: online (max,sum) of softmax logits
        float m = -1e30f, s = 0.f;
        for (int j = b0 + slot; j < b1; j += LPH) {
            int sn = csr_src[j];
            float e = asr[sn * H + hd] + ad;
            e = e > 0.f ? e : 0.2f * e;
            float mn = fmaxf(m, e);
            s = s * __expf(m - mn) + __expf(e - mn);
            m = mn;
        }
        #pragma unroll
        for (int off = 1; off < LPH; off <<= 1) {
            float mo = __shfl_xor(m, off);
            float so = __shfl_xor(s, off);
            float mn = fmaxf(m, mo);
            s = s * __expf(m - mn) + so * __expf(mo - mn);
            m = mn;
        }
        const float inv_s = 1.f / s;

        float acc[V];
        #pragma unroll
        for (int v = 0; v < V; v++) acc[v] = 0.f;

        // pass 2: chunk of LPH edges; zero-padded alpha; 4-edge gather groups
        for (int cbase = 0; cbase < deg; cbase += LPH) {
            const int nn = min(LPH, deg - cbase);
            int   sn_l = 0;
            float al_l = 0.f;
            if (slot < nn) {
                sn_l = csr_src[b0 + cbase + slot];
                float e = asr[sn_l * H + hd] + ad;
                e = e > 0.f ? e : 0.2f * e;
                al_l = __expf(e - m) * inv_s;
            }
            const int nn4 = (nn + 3) & ~3;   // <= LPH, shfl stays in head group
            for (int e4 = 0; e4 < nn4; e4 += 4) {
                int   s0 = __shfl(sn_l, lbase + e4 + 0);
                int   s1 = __shfl(sn_l, lbase + e4 + 1);
                int   s2 = __shfl(sn_l, lbase + e4 + 2);
                int   s3 = __shfl(sn_l, lbase + e4 + 3);
                float a0 = __shfl(al_l, lbase + e4 + 0);
                float a1 = __shfl(al_l, lbase + e4 + 1);
                float a2 = __shfl(al_l, lbase + e4 + 2);
                float a3 = __shfl(al_l, lbase + e4 + 3);
                gacc<ND>(xpd, s0 * STR + coff, a0, acc);
                gacc<ND>(xpd, s1 * STR + coff, a1, acc);
                gacc<ND>(xpd, s2 * STR + coff, a2, acc);
                gacc<ND>(xpd, s3 * STR + coff, a3, acc);
            }
        }
        #pragma unroll
        for (int v = 0; v < V; v++) acc[v] += bv[v];

        if constexpr (!LAST) {
            // LayerNorm over CT (within half-wave) + ELU, write bf16
            float lsum = 0.f, lsq = 0.f;
            #pragma unroll
            for (int v = 0; v < V; v++) { lsum += acc[v]; lsq = fmaf(acc[v], acc[v], lsq); }
            #pragma unroll
            for (int off = 1; off < LPN; off <<= 1) {
                lsum += __shfl_xor(lsum, off);
                lsq  += __shfl_xor(lsq,  off);
            }
            float mu  = lsum * (1.f / CT);
            float var = lsq  * (1.f / CT) - mu * mu;
            float rs  = rsqrtf(var + 1e-5f);
            unsigned int od[ND];
            #pragma unroll
            for (int k = 0; k < ND; k++) {
                float y0 = (acc[2 * k]     - mu) * rs * gv[2 * k]     + bev[2 * k];
                float y1 = (acc[2 * k + 1] - mu) * rs * gv[2 * k + 1] + bev[2 * k + 1];
                y0 = y0 > 0.f ? y0 : expm1f(y0);
                y1 = y1 > 0.f ? y1 : expm1f(y1);
                od[k] = (unsigned int)f2u(y0) | ((unsigned int)f2u(y1) << 16);
            }
            unsigned int* ob = (unsigned int*)outv + (size_t)n * STR + coff;
            if constexpr (ND == 4) *(uint4*)ob = make_uint4(od[0], od[1], od[2], od[3]);
            else                   *(uint2*)ob = make_uint2(od[0], od[1]);
        } else {
            if constexpr (OBF) {
                uint2 o;
                o.x = (unsigned int)f2u(acc[0]) | ((unsigned int)f2u(acc[1]) << 16);
                o.y = (unsigned int)f2u(acc[2]) | ((unsigned int)f2u(acc[3]) << 16);
                *(uint2*)((bf16*)outv + (size_t)n * CT + V * li) = o;
            } else {
                *(float4*)((float*)outv + (size_t)n * CT + V * li) =
                    make_float4(acc[0], acc[1], acc[2], acc[3]);
            }
        }
    }
}

// --------------------------------- launcher --------------------------------
extern "C" void kernel_launch(void* const* d_in, const int* in_sizes, int n_in,
                              void* d_out, int out_size, void* d_ws, size_t ws_size,
                              hipStream_t stream) {
    const void* x   = d_in[0];
    const void* ei  = d_in[1];
    const void* W1  = d_in[2];
    const void* W2  = d_in[8];
    const void* W3  = d_in[14];

    char* ws = (char*)d_ws;
    bf16*  xp     = (bf16*)(ws);                // [N,256] bf16 = 25,600,000 B
    bf16*  hbuf   = (bf16*)(ws + 25600000);     // [N,256] bf16; also hosts xb
    float* asr    = (float*)(ws + 51200000);    // 800,000 B (adst adjacent)
    float* adst   = (float*)(ws + 52000000);    // 800,000 B
    int*   counts = (int*)  (ws + 52800000);
    int*   scannd = (int*)  (ws + 53000000);
    int*   part   = (int*)  (ws + 53200000);
    int*   rowptr = (int*)  (ws + 53200256);
    int*   cursor = (int*)  (ws + 53400260);
    int*   csrsrc = (int*)  (ws + 53600260);
    int*   flags  = (int*)  (ws + 57000260);
    bf16*  Wt1    = (bf16*)(ws + 57000320);     // [256][128]
    bf16*  Wt2    = (bf16*)(ws + 57065856);     // [128][256]
    bf16*  Wt3    = (bf16*)(ws + 57131392);     // [128][128]
    float* params = (float*)(ws + 57164160);    // 2304 floats canonical fp32

    bf16* xb = hbuf;

    const int nb_scan = (N_NODES + SCAN_B - 1) / SCAN_B;
    const int AGGB    = (N_NODES / 2 + 3) / 4;  // 25000 node-pairs, 4 waves/block

    k_detect<<<1, 64, 0, stream>>>((const unsigned int*)x, (const unsigned int*)ei, flags);

    // CSR build
    k_zero<<<(N_NODES + 255) / 256, 256, 0, stream>>>(counts, N_NODES);
    k_hist<false><<<(E_TOT + 255) / 256, 256, 0, stream>>>(flags, ei, counts);
    k_hist<true ><<<(E_TOT + 255) / 256, 256, 0, stream>>>(flags, ei, counts);
    k_scan1<<<nb_scan, SCAN_B, 0, stream>>>(counts, scannd, part, N_NODES);
    k_scan2<<<1, 64, 0, stream>>>(part, nb_scan);
    k_scan3<<<(N_NODES + 255) / 256, 256, 0, stream>>>(counts, scannd, part, rowptr, cursor, N_NODES);
    k_scatter<false><<<(E_TOT + 255) / 256, 256, 0, stream>>>(flags, ei, cursor, csrsrc);
    k_scatter<true ><<<(E_TOT + 255) / 256, 256, 0, stream>>>(flags, ei, cursor, csrsrc);

    // canonicalize inputs
    const int n4 = N_NODES * 128 / 4;
    k_prepx<false><<<(n4 + 255) / 256, 256, 0, stream>>>(flags, x, xb, n4);
    k_prepx<true ><<<(n4 + 255) / 256, 256, 0, stream>>>(flags, x, xb, n4);
    k_prepw<128, 256, false><<<128, 256, 0, stream>>>(flags, W1, Wt1);
    k_prepw<128, 256, true ><<<128, 256, 0, stream>>>(flags, W1, Wt1);
    k_prepw<256, 128, false><<<128, 256, 0, stream>>>(flags, W2, Wt2);
    k_prepw<256, 128, true ><<<128, 256, 0, stream>>>(flags, W2, Wt2);
    k_prepw<128, 128, false><<<64, 256, 0, stream>>>(flags, W3, Wt3);
    k_prepw<128, 128, true ><<<64, 256, 0, stream>>>(flags, W3, Wt3);

    PrepArgs pa;
    const int srcs[13] = {3, 4, 5, 6, 7, 9, 10, 11, 12, 13, 15, 16, 17};
    const int offs[13] = {0, 256, 512, 768, 1024, 1280, 1408, 1536, 1664, 1792, 1920, 2048, 2176};
    const int lens[13] = {256, 256, 256, 256, 256, 128, 128, 128, 128, 128, 128, 128, 128};
    for (int i = 0; i < 13; i++) { pa.src[i] = d_in[srcs[i]]; pa.off[i] = offs[i]; pa.len[i] = lens[i]; }
    k_prep_small<false><<<13, 256, 0, stream>>>(flags, pa, params);
    k_prep_small<true ><<<13, 256, 0, stream>>>(flags, pa, params);

    // ---- layer 1: in 128 -> xp [N,256], H=4
    k_zero<<<(400000 + 255) / 256, 256, 0, stream>>>((int*)asr, 400000);  // asr+adst
    k_gemm_mfma2<128, 256, 4, 4><<<768, 256, 0, stream>>>(xb, Wt1, xp, params + 0, params + 256, asr, adst);
    k_agg3<256, 4, false, false><<<AGGB, 256, 0, stream>>>(flags, xp, asr, adst, rowptr, csrsrc,
                                                           params + 512, params + 768, params + 1024, hbuf);

    // ---- layer 2: in 256 -> xp [N,128], H=2
    k_zero<<<(400000 + 255) / 256, 256, 0, stream>>>((int*)asr, 400000);
    k_gemm_mfma2<256, 128, 2, 2><<<768, 256, 0, stream>>>(hbuf, Wt2, xp, params + 1280, params + 1408, asr, adst);
    k_agg3<128, 2, false, false><<<AGGB, 256, 0, stream>>>(flags, xp, asr, adst, rowptr, csrsrc,
                                                           params + 1536, params + 1664, params + 1792, hbuf);

    // ---- layer 3: in 128 -> xp [N,128], H=1; write d_out
    k_zero<<<(400000 + 255) / 256, 256, 0, stream>>>((int*)asr, 400000);
    k_gemm_mfma2<128, 128, 2, 1><<<768, 256, 0, stream>>>(hbuf, Wt3, xp, params + 1920, params + 2048, asr, adst);
    k_agg3<128, 1, true, false><<<AGGB, 256, 0, stream>>>(flags, xp, asr, adst, rowptr, csrsrc,
                                                          params + 2176, nullptr, nullptr, d_out);
    k_agg3<128, 1, true, true ><<<AGGB, 256, 0, stream>>>(flags, xp, asr, adst, rowptr, csrsrc,
                                                          params + 2176, nullptr, nullptr, d_out);
}